// Round 1
// baseline (314.208 us; speedup 1.0000x reference)
//
#include <hip/hip_runtime.h>

#define BX 4
#define VX 4
#define NN 1000
#define HEADS_ 4
#define OUTF 32
#define DM 128
#define EE 64000
#define NTOT 4000
#define ETOT 68000

// ---------------------------------------------------------------- h = x @ W^T
// x: (16000, 64) row-major; W: (128, 64) row-major; hbuf: (16000, 128)
__global__ __launch_bounds__(128) void h_kernel(const float* __restrict__ x,
                                                const float* __restrict__ W,
                                                float* __restrict__ hbuf) {
  int t = threadIdx.x;
  const float4* W4 = (const float4*)W;
  float4 w4[16];
#pragma unroll
  for (int j = 0; j < 16; ++j) w4[j] = W4[t * 16 + j];  // W row t in registers
  __shared__ float xs[128];
  int row0 = blockIdx.x * 128;  // 125 blocks x 128 rows
  for (int p = 0; p < 64; ++p) {
    int r = row0 + p * 2;
    __syncthreads();
    xs[t] = x[r * 64 + t];  // two consecutive rows, coalesced
    __syncthreads();
    float acc0 = 0.f, acc1 = 0.f;
#pragma unroll
    for (int j = 0; j < 16; ++j) {
      float4 w = w4[j];
      acc0 += xs[4*j+0]*w.x + xs[4*j+1]*w.y + xs[4*j+2]*w.z + xs[4*j+3]*w.w;
      acc1 += xs[64+4*j+0]*w.x + xs[64+4*j+1]*w.y + xs[64+4*j+2]*w.z + xs[64+4*j+3]*w.w;
    }
    hbuf[r * 128 + t] = acc0;
    hbuf[(r + 1) * 128 + t] = acc1;
  }
}

// ------------------------------------------------- per-node score halves
// s_src[j,h] = sum_k att[0,h,k]    * lrelu(h_flat[j,h,k])
// s_dst[j,h] = sum_k att[0,h,32+k] * lrelu(h_flat[j,h,k])
// h_flat[j] = hbuf row j (b=0,v=0 block) if j<1000 else 0
__global__ void node_score_kernel(const float* __restrict__ hbuf,
                                  const float* __restrict__ att,
                                  float* __restrict__ ssrc,
                                  float* __restrict__ sdst) {
  int j = blockIdx.x * blockDim.x + threadIdx.x;
  if (j >= NTOT) return;
  if (j < NN) {
#pragma unroll
    for (int h = 0; h < HEADS_; ++h) {
      float a0 = 0.f, a1 = 0.f;
#pragma unroll
      for (int k = 0; k < OUTF; ++k) {
        float g = hbuf[j * DM + h * OUTF + k];
        float lr = g > 0.f ? g : 0.2f * g;
        a0 += att[h * 64 + k] * lr;
        a1 += att[h * 64 + 32 + k] * lr;
      }
      ssrc[j * HEADS_ + h] = a0;
      sdst[j * HEADS_ + h] = a1;
    }
  } else {
#pragma unroll
    for (int h = 0; h < HEADS_; ++h) {
      ssrc[j * HEADS_ + h] = 0.f;
      sdst[j * HEADS_ + h] = 0.f;
    }
  }
}

// -------------------------------------- per-edge exp(score) + denom atomics
__global__ void edge_score_kernel(const int* __restrict__ ei,
                                  const float* __restrict__ ssrc,
                                  const float* __restrict__ sdst,
                                  float* __restrict__ exbuf,
                                  float* __restrict__ denom) {
  int e = blockIdx.x * blockDim.x + threadIdx.x;
  if (e >= ETOT) return;
  int s, d;
  if (e < EE) { s = ei[e]; d = ei[EE + e]; }
  else { s = d = e - EE; }  // self loops
#pragma unroll
  for (int h = 0; h < HEADS_; ++h) {
    float sc = ssrc[s * HEADS_ + h] + sdst[d * HEADS_ + h];
    float ex = __expf(sc);  // softmax shift-invariant; scores O(1), no max pass
    exbuf[e * HEADS_ + h] = ex;
    atomicAdd(&denom[d * HEADS_ + h], ex);
  }
}

// -------------------------------------------- aggregation (scatter into out)
// out[b,v,n,:] += alpha[e,h] * h[b,v,src_local,:] for edges with src,dst in block b
__global__ __launch_bounds__(128) void aggregate_kernel(const int* __restrict__ ei,
                                                        const float* __restrict__ exbuf,
                                                        const float* __restrict__ denom,
                                                        const float* __restrict__ hbuf,
                                                        float* __restrict__ out) {
  int e = blockIdx.x;
  int s, d;
  if (e < EE) { s = ei[e]; d = ei[EE + e]; }
  else { s = d = e - EE; }
  int b = d / NN;
  if (s / NN != b) return;  // h_full is block-diagonal: cross-block msgs are zero
  int t = threadIdx.x;
  int h = t >> 5;
  float alpha = exbuf[e * HEADS_ + h] / (denom[d * HEADS_ + h] + 1e-16f);
  int n = d - b * NN, sl = s - b * NN;
#pragma unroll
  for (int v = 0; v < VX; ++v) {
    float val = hbuf[((b * VX + v) * NN + sl) * DM + t];
    atomicAdd(&out[((b * VX + v) * NN + n) * DM + t], alpha * val);
  }
}

// ------------------------------------------------ MHA over V per node, in-place
__global__ __launch_bounds__(128) void mha_kernel(const float* __restrict__ inw,
                                                  const float* __restrict__ inb,
                                                  const float* __restrict__ outw,
                                                  const float* __restrict__ outb,
                                                  const float* __restrict__ bias,
                                                  float* __restrict__ out) {
  int node = blockIdx.x;
  int b = node / NN, n = node % NN;
  int t = threadIdx.x;
  __shared__ float seq[VX][DM];
  __shared__ float qs[VX][DM], ks[VX][DM], vs[VX][DM];
  __shared__ float aw[VX][HEADS_][VX];
  __shared__ float ao[VX][DM];
#pragma unroll
  for (int v = 0; v < VX; ++v)
    seq[v][t] = out[((b * VX + v) * NN + n) * DM + t];
  __syncthreads();
  {  // qkv projection: thread t computes channel t for q,k,v across all views
    const float4* inw4 = (const float4*)inw;
    float aq[VX], ak[VX], av[VX];
#pragma unroll
    for (int v = 0; v < VX; ++v) {
      aq[v] = inb[t]; ak[v] = inb[DM + t]; av[v] = inb[2 * DM + t];
    }
    for (int j4 = 0; j4 < DM / 4; ++j4) {
      float4 wq = inw4[t * (DM / 4) + j4];
      float4 wk = inw4[(DM + t) * (DM / 4) + j4];
      float4 wv = inw4[(2 * DM + t) * (DM / 4) + j4];
#pragma unroll
      for (int v = 0; v < VX; ++v) {
        float s0 = seq[v][4*j4+0], s1 = seq[v][4*j4+1];
        float s2 = seq[v][4*j4+2], s3 = seq[v][4*j4+3];
        aq[v] += s0*wq.x + s1*wq.y + s2*wq.z + s3*wq.w;
        ak[v] += s0*wk.x + s1*wk.y + s2*wk.z + s3*wk.w;
        av[v] += s0*wv.x + s1*wv.y + s2*wv.z + s3*wv.w;
      }
    }
#pragma unroll
    for (int v = 0; v < VX; ++v) { qs[v][t] = aq[v]; ks[v][t] = ak[v]; vs[v][t] = av[v]; }
  }
  __syncthreads();
  if (t < 64) {  // 64 dot products: (vq, vk, h), each length 32
    int vq = t >> 4, vk = (t >> 2) & 3, h = t & 3;
    float acc = 0.f;
#pragma unroll
    for (int kd = 0; kd < 32; ++kd) acc += qs[vq][h * 32 + kd] * ks[vk][h * 32 + kd];
    aw[vq][h][vk] = acc * 0.17677669529663687f;  // 1/sqrt(32)
  }
  __syncthreads();
  if (t < 16) {  // softmax over vk per (vq, h)
    int vq = t >> 2, h = t & 3;
    float m = aw[vq][h][0];
    for (int i = 1; i < 4; ++i) m = fmaxf(m, aw[vq][h][i]);
    float e[4], s = 0.f;
    for (int i = 0; i < 4; ++i) { e[i] = __expf(aw[vq][h][i] - m); s += e[i]; }
    for (int i = 0; i < 4; ++i) aw[vq][h][i] = e[i] / s;
  }
  __syncthreads();
  {  // ao[vq][t] = sum_vk aw[vq][h][vk] * vs[vk][t]
    int h = t >> 5;
#pragma unroll
    for (int vq = 0; vq < VX; ++vq) {
      float acc = 0.f;
#pragma unroll
      for (int vk = 0; vk < VX; ++vk) acc += aw[vq][h][vk] * vs[vk][t];
      ao[vq][t] = acc;
    }
  }
  __syncthreads();
  {  // out_proj + out_proj_b + bias, write back in-place
    const float4* outw4 = (const float4*)outw;
    float acc[VX];
    float base = outb[t] + bias[t];
#pragma unroll
    for (int vq = 0; vq < VX; ++vq) acc[vq] = base;
    for (int j4 = 0; j4 < DM / 4; ++j4) {
      float4 w = outw4[t * (DM / 4) + j4];
#pragma unroll
      for (int vq = 0; vq < VX; ++vq) {
        acc[vq] += ao[vq][4*j4+0]*w.x + ao[vq][4*j4+1]*w.y
                 + ao[vq][4*j4+2]*w.z + ao[vq][4*j4+3]*w.w;
      }
    }
#pragma unroll
    for (int vq = 0; vq < VX; ++vq)
      out[((b * VX + vq) * NN + n) * DM + t] = acc[vq];
  }
}

extern "C" void kernel_launch(void* const* d_in, const int* in_sizes, int n_in,
                              void* d_out, int out_size, void* d_ws, size_t ws_size,
                              hipStream_t stream) {
  const float* x    = (const float*)d_in[0];
  const float* W    = (const float*)d_in[1];
  const float* att  = (const float*)d_in[2];
  const float* inw  = (const float*)d_in[3];
  const float* inb  = (const float*)d_in[4];
  const float* outw = (const float*)d_in[5];
  const float* outb = (const float*)d_in[6];
  const float* bias = (const float*)d_in[7];
  const int*   ei   = (const int*)d_in[8];
  float* out = (float*)d_out;

  float* ws    = (float*)d_ws;
  float* hbuf  = ws;                   // 16000*128 = 2,048,000 floats
  float* ssrc  = hbuf + 2048000;       // 16,000
  float* sdst  = ssrc + 16000;         // 16,000
  float* denom = sdst + 16000;         // 16,000
  float* exbuf = denom + 16000;        // 272,000
  // total ~9.4 MB of d_ws

  hipMemsetAsync(d_out, 0, (size_t)out_size * sizeof(float), stream);   // atomics target
  hipMemsetAsync(denom, 0, 16000 * sizeof(float), stream);

  h_kernel<<<125, 128, 0, stream>>>(x, W, hbuf);
  node_score_kernel<<<(NTOT + 255) / 256, 256, 0, stream>>>(hbuf, att, ssrc, sdst);
  edge_score_kernel<<<(ETOT + 255) / 256, 256, 0, stream>>>(ei, ssrc, sdst, exbuf, denom);
  aggregate_kernel<<<ETOT, 128, 0, stream>>>(ei, exbuf, denom, hbuf, out);
  mha_kernel<<<NTOT, 128, 0, stream>>>(inw, inb, outw, outb, bias, out);
}